// Round 25
// baseline (44.044 us; speedup 1.0000x reference)
//
#include <hip/hip_runtime.h>
#include <hip/hip_fp16.h>
#include <math.h>

// GaussianMixtureLoss — R25: AMPLIFIED PROBE on R23 (sacrificial).
// R23's MFMA inner tile-loop repeated REP=8 (asm clobber forces re-exec of
// ds_read+MFMA+consume); comb write scaled 1/REP so output is identical.
// Decode: inner = (T - 15.03)/7. gm_main surfaces in the counter table ->
// first direct look at MfmaUtil / VALUBusy / VGPR for the MFMA structure.
#define BATCH 4
#define NPTS 4096
#define NMIX 4096
#define THREADS 512
#define PPB 32
#define NBLOCKS ((BATCH * NPTS) / PPB)  // 512
#define NTILES (NMIX / 32)
#define TPW (NTILES / 8)       // 16 tiles per wave
#define REP 8

#define LN2 0.6931471805599453f
#define CONST_TERM 0.9189385332046727f
#define INV_COUNT (1.0f / (float)(BATCH * NPTS))
#define SQK      3478.8221f
#define B4VAL    32768.0f
#define A4BASE   32497.587f
#define A4SLOPE  (-184.66497f)

typedef _Float16 f16x4 __attribute__((ext_vector_type(4)));
typedef float f32x16 __attribute__((ext_vector_type(16)));

__device__ __forceinline__ float fast_log2(float x) {
#if __has_builtin(__builtin_amdgcn_logf)
  return __builtin_amdgcn_logf(x);
#else
  return log2f(x);
#endif
}

__device__ __forceinline__ uint32_t pack_h2(float a, float b) {
  __half2 h = __float22half2_rn(make_float2(a, b));
  return __builtin_bit_cast(uint32_t, h);
}

__global__ __launch_bounds__(THREADS) void gm_main(
    const float* __restrict__ pred, const float* __restrict__ gt,
    float* __restrict__ bsum) {
  __shared__ __align__(8) uint2 gsh[NMIX];  // 32 KB
  __shared__ float comb[8][PPB];

  const int t = threadIdx.x;
  const int b = blockIdx.x >> 7;
  const int n0 = (blockIdx.x & 127) * PPB;
  const int lane = t & 63;
  const int w = t >> 6;

  // stage mixture quads (float2-pair pattern, kept from R24 - harmless)
#pragma unroll
  for (int i = 0; i < NMIX / (2 * THREADS); ++i) {
    int s = t + i * THREADS;
    const float2* g = (const float2*)(gt + ((size_t)(b * NMIX + 2 * s)) * 3);
    float2 g01 = g[0], g23 = g[1], g45 = g[2];
    float n20 = fmaf(g01.x, g01.x, fmaf(g01.y, g01.y, g23.x * g23.x));
    float n21 = fmaf(g23.y, g23.y, fmaf(g45.x, g45.x, g45.y * g45.y));
    float a40 = fmaf(n20, A4SLOPE, A4BASE);
    float a41 = fmaf(n21, A4SLOPE, A4BASE);
    gsh[2 * s] = make_uint2(pack_h2(SQK * g01.x, SQK * g01.y),
                            pack_h2(SQK * g23.x, a40));
    gsh[2 * s + 1] = make_uint2(pack_h2(SQK * g23.y, SQK * g45.x),
                                pack_h2(SQK * g45.y, a41));
  }

  // A-frag (points), loop-invariant
  f16x4 afrag;
  {
    uint2 au = make_uint2(0u, 0u);
    if (lane < 32) {
      const float* p = pred + (size_t)(b * NPTS + n0 + lane) * 3;
      au = make_uint2(pack_h2(SQK * p[0], SQK * p[1]),
                      pack_h2(SQK * p[2], B4VAL));
    }
    afrag = __builtin_bit_cast(f16x4, au);
  }

  __syncthreads();

  // inner (R23 form), repeated REP times
  f32x16 acc = 0.0f;
  {
    const uint2* bbase = gsh + w * (TPW * 32) + (lane & 31);
    const bool lo = lane < 32;
    const f32x16 czero = 0.0f;
#pragma unroll 1
    for (int rep = 0; rep < REP; ++rep) {
      asm volatile("" ::: "memory");
#pragma unroll 4
      for (int j = 0; j < TPW; ++j) {
        uint2 raw = bbase[j * 32];
        raw.x = lo ? raw.x : 0u;
        raw.y = lo ? raw.y : 0u;
        f16x4 bfrag = __builtin_bit_cast(f16x4, raw);
        f32x16 d = __builtin_amdgcn_mfma_f32_32x32x8f16(afrag, bfrag, czero, 0, 0, 0);
#pragma unroll
        for (int r = 0; r < 16; ++r)
          acc[r] += __builtin_bit_cast(float, (int)d[r]);
      }
    }
  }

  // col-reduce across 32 mixture cols
#pragma unroll
  for (int mask = 1; mask <= 16; mask <<= 1) {
#pragma unroll
    for (int r = 0; r < 16; ++r) acc[r] += __shfl_xor(acc[r], mask, 64);
  }

  if ((lane & 31) == 0) {
#pragma unroll
    for (int r = 0; r < 16; ++r)
      comb[w][(r & 3) + 8 * (r >> 2) + 4 * (lane >> 5)] =
          acc[r] * (1.0f / (float)REP);
  }
  __syncthreads();

  if (t < PPB) {
    float s = ((comb[0][t] + comb[1][t]) + (comb[2][t] + comb[3][t])) +
              ((comb[4][t] + comb[5][t]) + (comb[6][t] + comb[7][t]));
    const float* p = pred + (size_t)(b * NPTS + n0 + t) * 3;
    float hp2 = 0.5f * (p[0] * p[0] + p[1] * p[1] + p[2] * p[2]);
    float ll = (LN2 * fast_log2(s) - hp2) * INV_COUNT;
#pragma unroll
    for (int off = 16; off > 0; off >>= 1) ll += __shfl_down(ll, off, 32);
    if (t == 0) bsum[blockIdx.x] = ll;
  }
}

__global__ __launch_bounds__(256) void gm_reduce(
    const float* __restrict__ bsum, float* __restrict__ out) {
  const int t = threadIdx.x;
  float v = bsum[t] + bsum[t + 256];
  for (int off = 32; off > 0; off >>= 1) v += __shfl_down(v, off, 64);
  __shared__ float w[4];
  if ((t & 63) == 0) w[t >> 6] = v;
  __syncthreads();
  if (t == 0) out[0] = CONST_TERM - ((w[0] + w[1]) + (w[2] + w[3]));
}

extern "C" void kernel_launch(void* const* d_in, const int* in_sizes, int n_in,
                              void* d_out, int out_size, void* d_ws, size_t ws_size,
                              hipStream_t stream) {
  const float* pred = (const float*)d_in[0];
  const float* gt   = (const float*)d_in[1];
  float* out = (float*)d_out;
  float* bsum = (float*)d_ws;

  gm_main<<<NBLOCKS, THREADS, 0, stream>>>(pred, gt, bsum);
  gm_reduce<<<1, 256, 0, stream>>>(bsum, out);
}

// Round 26
// 18.084 us; speedup vs baseline: 2.4355x; 2.4355x over previous
//
#include <hip/hip_runtime.h>
#include <hip/hip_fp16.h>
#include <math.h>

// GaussianMixtureLoss: loss = CONST - mean_{b,n}( ln sum_m exp(p·g - |g|²/2) - |p|²/2 )
// B=4, N=4096, M=4096, D=3, SIGMA=1.
// R26: R23 MFMA structure, THREADS 512 -> 1024 (16 waves/block, TPW 16->8).
// R25 probe: inner 4.1us, VGPR=28 -> no d double-buffer possible, each tile
// serializes MFMA latency + consume; VALUBusy 50% at 4 waves/SIMD. This
// config: 2 blocks/CU x 16 waves = 8 waves/SIMD - double the independent
// MFMA<->consume streams to hide the serialization. Staging aggregate,
// LDS (34KB), inner math, C/D layout (m74/m101) unchanged.
#define BATCH 4
#define NPTS 4096
#define NMIX 4096
#define THREADS 1024
#define PPB 32                 // points per block (one 32-row MFMA tile)
#define NBLOCKS ((BATCH * NPTS) / PPB)  // 512
#define NTILES (NMIX / 32)     // 128 mixture tiles per batch
#define NWAVES 16
#define TPW (NTILES / NWAVES)  // 8 tiles per wave

#define LN2 0.6931471805599453f
#define CONST_TERM 0.9189385332046727f  // 0.5*log(2*pi)
#define INV_COUNT (1.0f / (float)(BATCH * NPTS))
// Schraudolph: K = 2^23*log2(e); BIAS = 2^23*(127-0.0563)
#define SQK      3478.8221f          // sqrt(K)
#define B4VAL    32768.0f            // exact in f16
#define A4BASE   32497.587f          // BIAS / 32768
#define A4SLOPE  (-184.66497f)       // -(K/2) / 32768

typedef _Float16 f16x4 __attribute__((ext_vector_type(4)));
typedef float f32x16 __attribute__((ext_vector_type(16)));

__device__ __forceinline__ float fast_log2(float x) {
#if __has_builtin(__builtin_amdgcn_logf)
  return __builtin_amdgcn_logf(x);
#else
  return log2f(x);
#endif
}

__device__ __forceinline__ uint32_t pack_h2(float a, float b) {
  __half2 h = __float22half2_rn(make_float2(a, b));
  return __builtin_bit_cast(uint32_t, h);
}

__global__ __launch_bounds__(THREADS) void gm_main(
    const float* __restrict__ pred, const float* __restrict__ gt,
    float* __restrict__ bsum) {
  __shared__ __align__(8) uint2 gsh[NMIX];   // 32 KB mixture f16 quads
  __shared__ float comb[NWAVES][PPB];        // 2 KB per-wave partial rows

  const int t = threadIdx.x;
  const int b = blockIdx.x >> 7;            // 128 blocks per batch
  const int n0 = (blockIdx.x & 127) * PPB;
  const int lane = t & 63;
  const int w = t >> 6;                     // wave 0..15

  // ---- stage mixture quads (sqrtK*g, a4): float2-pair pattern ----
#pragma unroll
  for (int i = 0; i < NMIX / (2 * THREADS); ++i) {  // 2 pairs per thread
    int s = t + i * THREADS;  // pair index 0..2047
    const float2* g = (const float2*)(gt + ((size_t)(b * NMIX + 2 * s)) * 3);
    float2 g01 = g[0], g23 = g[1], g45 = g[2];
    float n20 = fmaf(g01.x, g01.x, fmaf(g01.y, g01.y, g23.x * g23.x));
    float n21 = fmaf(g23.y, g23.y, fmaf(g45.x, g45.x, g45.y * g45.y));
    float a40 = fmaf(n20, A4SLOPE, A4BASE);
    float a41 = fmaf(n21, A4SLOPE, A4BASE);
    gsh[2 * s] = make_uint2(pack_h2(SQK * g01.x, SQK * g01.y),
                            pack_h2(SQK * g23.x, a40));
    gsh[2 * s + 1] = make_uint2(pack_h2(SQK * g23.y, SQK * g45.x),
                                pack_h2(SQK * g45.y, a41));
  }

  // ---- A-frag (points), loop-invariant: lane<32 -> point n0+lane ----
  f16x4 afrag;
  {
    uint2 au = make_uint2(0u, 0u);
    if (lane < 32) {
      const float* p = pred + (size_t)(b * NPTS + n0 + lane) * 3;
      au = make_uint2(pack_h2(SQK * p[0], SQK * p[1]),
                      pack_h2(SQK * p[2], B4VAL));
    }
    afrag = __builtin_bit_cast(f16x4, au);
  }

  __syncthreads();

  // ---- inner: 8 tiles/wave, MFMA + Schraudolph cvt/add consume ----
  f32x16 acc = 0.0f;
  {
    const uint2* bbase = gsh + w * (TPW * 32) + (lane & 31);
    const bool lo = lane < 32;
    const f32x16 czero = 0.0f;
#pragma unroll 4
    for (int j = 0; j < TPW; ++j) {
      uint2 raw = bbase[j * 32];            // ds_read_b64
      raw.x = lo ? raw.x : 0u;              // zero k=4..7 lanes
      raw.y = lo ? raw.y : 0u;
      f16x4 bfrag = __builtin_bit_cast(f16x4, raw);
      f32x16 d = __builtin_amdgcn_mfma_f32_32x32x8f16(afrag, bfrag, czero, 0, 0, 0);
#pragma unroll
      for (int r = 0; r < 16; ++r)
        acc[r] += __builtin_bit_cast(float, (int)d[r]);  // Schraudolph exp
    }
  }

  // ---- col-reduce: sum 32 mixture-cols (xor over lane bits 0-4) ----
#pragma unroll
  for (int mask = 1; mask <= 16; mask <<= 1) {
#pragma unroll
    for (int r = 0; r < 16; ++r) acc[r] += __shfl_xor(acc[r], mask, 64);
  }

  // rows: (r&3) + 8*(r>>2) + 4*(lane>>5); lanes 0 and 32 write 16 rows each
  if ((lane & 31) == 0) {
#pragma unroll
    for (int r = 0; r < 16; ++r)
      comb[w][(r & 3) + 8 * (r >> 2) + 4 * (lane >> 5)] = acc[r];
  }
  __syncthreads();

  // ---- tail: combine 16 waves, log, hp2, block reduce ----
  if (t < PPB) {
    float s = 0.f;
#pragma unroll
    for (int ww = 0; ww < NWAVES; ++ww) s += comb[ww][t];
    const float* p = pred + (size_t)(b * NPTS + n0 + t) * 3;
    float hp2 = 0.5f * (p[0] * p[0] + p[1] * p[1] + p[2] * p[2]);
    float ll = (LN2 * fast_log2(s) - hp2) * INV_COUNT;
#pragma unroll
    for (int off = 16; off > 0; off >>= 1) ll += __shfl_down(ll, off, 32);
    if (t == 0) bsum[blockIdx.x] = ll;
  }
}

__global__ __launch_bounds__(256) void gm_reduce(
    const float* __restrict__ bsum, float* __restrict__ out) {
  const int t = threadIdx.x;
  float v = bsum[t] + bsum[t + 256];  // 512 entries
  for (int off = 32; off > 0; off >>= 1) v += __shfl_down(v, off, 64);
  __shared__ float w[4];
  if ((t & 63) == 0) w[t >> 6] = v;
  __syncthreads();
  if (t == 0) out[0] = CONST_TERM - ((w[0] + w[1]) + (w[2] + w[3]));
}

extern "C" void kernel_launch(void* const* d_in, const int* in_sizes, int n_in,
                              void* d_out, int out_size, void* d_ws, size_t ws_size,
                              hipStream_t stream) {
  const float* pred = (const float*)d_in[0];
  const float* gt   = (const float*)d_in[1];
  float* out = (float*)d_out;
  float* bsum = (float*)d_ws;  // 512 floats, fully overwritten every call

  gm_main<<<NBLOCKS, THREADS, 0, stream>>>(pred, gt, bsum);
  gm_reduce<<<1, 256, 0, stream>>>(bsum, out);
}